// Round 3
// baseline (437.336 us; speedup 1.0000x reference)
//
#include <hip/hip_runtime.h>
#include <stdint.h>

#define BB 4
#define HH 256
#define WW 256
#define CC 128
#define NN 32
#define NPIX (HH*WW)            // 65536
#define RANK 52428u             // 0-based order-stat index: 0.8*(65536-1) exactly
#define TOTAL_PAIRS 1984.0f     // B * N*(N-1)/2

// workspace byte offsets
// sm (u32): [4+b]=bin16, [8+b]=r2, [12+b]=thr_key
#define OFF_SM      0                              // 4 KiB
#define OFF_H16     4096                           // B*65536 u32 = 1 MiB
#define OFF_H3      (OFF_H16 + BB*65536*4)         // B*65536 u32 = 1 MiB
#define OFF_GSPLIT  (OFF_H3 + BB*65536*4)          // B*12288 shorts = 96 KiB
#define OFF_GN      (OFF_GSPLIT + BB*12288*2)      // B*N floats (pad 4 KiB)
#define OFF_KEYS    (OFF_GN + 4096)                // B*NPIX u32 = 1 MiB
#define OFF_P       (OFF_KEYS + BB*NPIX*4)         // B*NPIX i32 = 1 MiB
#define MEMSET_BYTES OFF_GSPLIT                    // sm + h16 + h3

typedef __attribute__((ext_vector_type(8))) short short8;
typedef __attribute__((ext_vector_type(4))) float f32x4;

// 3-way bf16 split via truncation; each residual subtraction is exact.
// f ~= hi+mid+lo with residual <= 2^-24 |f|.
__device__ __forceinline__ void split3(float f, short &hi, short &mid, short &lo) {
    uint32_t u  = __float_as_uint(f);
    uint32_t hb = u & 0xffff0000u;
    hi = (short)(hb >> 16);
    float r1 = f - __uint_as_float(hb);
    uint32_t mb = __float_as_uint(r1) & 0xffff0000u;
    mid = (short)(mb >> 16);
    float r2 = r1 - __uint_as_float(mb);
    lo = (short)(__float_as_uint(r2) >> 16);
}

// gsplit linear layout (shorts), identical to LDS layout used by k_d2mfma:
//   idx = b*12288 + s*4096 + (t*4 + kk)*512 + lane*8 + j
//   s: split {hi,mid,lo}; t: n-tile (n>>4); kk: k-chunk (c>>5);
//   lane = ((c&31)>>3)*16 + (n&15); j = c&7   (B-operand fragment order)

// ---------------- K0: gather center features -> split fragments + |g|^2 ----------------
__global__ void k_gather(const float* __restrict__ feat, const int* __restrict__ centers,
                         short* __restrict__ gsplit, float* __restrict__ gnorm) {
    int b = blockIdx.x / NN, n = blockIdx.x % NN;
    int cy = centers[(b*NN + n)*2 + 0];
    int cx = centers[(b*NN + n)*2 + 1];
    int c = threadIdx.x; // 128 threads
    float v = feat[((size_t)b*NPIX + cy*WW + cx)*CC + c];
    short hi, mid, lo; split3(v, hi, mid, lo);
    int t = n >> 4, kk = c >> 5, q = (c & 31) >> 3, j = c & 7;
    int lane = q*16 + (n & 15);
    size_t base = (size_t)b*12288 + (size_t)(t*4 + kk)*512 + lane*8 + j;
    gsplit[base]          = hi;
    gsplit[base + 4096]   = mid;
    gsplit[base + 8192]   = lo;
    __shared__ float s[128];
    s[c] = v*v;
    __syncthreads();
    for (int off = 64; off > 0; off >>= 1) {
        if (c < off) s[c] += s[c+off];
        __syncthreads();
    }
    if (c == 0) gnorm[b*NN + n] = s[0];
}

// ---------------- K1: MFMA distance kernel: min_n ||f-g_n||^2 -> key (+16-bit hist) ------
// block = 256 threads = 4 waves; wave handles 16 pixels; block 64 pixels.
__global__ __launch_bounds__(256) void k_d2mfma(const float* __restrict__ feat,
        const short* __restrict__ gsplit, const float* __restrict__ gnorm,
        uint32_t* __restrict__ keys, uint32_t* __restrict__ h16) {
    __shared__ short gB[12288];   // 24 KiB: [s][t*4+kk][lane][8]
    int b = blockIdx.y;

    // stage pre-split G fragments (coalesced block copy: 1536 uint4)
    {
        const uint4* src = (const uint4*)(gsplit + (size_t)b*12288);
        uint4* dst = (uint4*)gB;
        #pragma unroll
        for (int i = 0; i < 6; i++) dst[threadIdx.x + i*256] = src[threadIdx.x + i*256];
    }
    __syncthreads();

    int wv = threadIdx.x >> 6, L = threadIdx.x & 63;
    int m = L & 15, q = L >> 4;
    int p0 = blockIdx.x*64 + wv*16;
    const float* fp = feat + ((size_t)b*NPIX + p0 + m)*CC + q*8;

    f32x4 acc[2] = {{0.f,0.f,0.f,0.f},{0.f,0.f,0.f,0.f}};
    float fn = 0.f;

    #pragma unroll
    for (int kk = 0; kk < 4; kk++) {
        float4 fa = *(const float4*)(fp + kk*32);
        float4 fb = *(const float4*)(fp + kk*32 + 4);
        float fs[8] = {fa.x,fa.y,fa.z,fa.w,fb.x,fb.y,fb.z,fb.w};
        short8 ahi, amid, alo;
        #pragma unroll
        for (int j = 0; j < 8; j++) {
            float f = fs[j];
            fn = fmaf(f, f, fn);
            short h, md, lw; split3(f, h, md, lw);
            ahi[j] = h; amid[j] = md; alo[j] = lw;
        }
        #pragma unroll
        for (int t = 0; t < 2; t++) {
            int off = (t*4 + kk)*512 + L*8;
            short8 bhi = *(const short8*)&gB[off];
            short8 bmd = *(const short8*)&gB[off + 4096];
            short8 blo = *(const short8*)&gB[off + 8192];
            // 6 significant split products: hi*hi, hi*mid, mid*hi, hi*lo, mid*mid, lo*hi
            acc[t] = __builtin_amdgcn_mfma_f32_16x16x32_bf16(ahi,  bhi, acc[t], 0,0,0);
            acc[t] = __builtin_amdgcn_mfma_f32_16x16x32_bf16(ahi,  bmd, acc[t], 0,0,0);
            acc[t] = __builtin_amdgcn_mfma_f32_16x16x32_bf16(amid, bhi, acc[t], 0,0,0);
            acc[t] = __builtin_amdgcn_mfma_f32_16x16x32_bf16(ahi,  blo, acc[t], 0,0,0);
            acc[t] = __builtin_amdgcn_mfma_f32_16x16x32_bf16(amid, bmd, acc[t], 0,0,0);
            acc[t] = __builtin_amdgcn_mfma_f32_16x16x32_bf16(alo,  bhi, acc[t], 0,0,0);
        }
    }

    // fn: reduce quad partials -> lanes with (L&15)==p hold full |f_p|^2
    fn += __shfl_xor(fn, 16);
    fn += __shfl_xor(fn, 32);

    float gn0 = gnorm[b*NN + m];
    float gn1 = gnorm[b*NN + 16 + m];

    // C layout: col(n) = L&15, row(pixel) = q*4 + reg
    float vmin[4];
    #pragma unroll
    for (int r = 0; r < 4; r++) {
        float fnr = __shfl(fn, q*4 + r);   // lane (q*4+r) holds fn of pixel p0+q*4+r
        float d0 = fnr + gn0 - 2.f*acc[0][r];
        float d1 = fnr + gn1 - 2.f*acc[1][r];
        float v = fminf(d0, d1);
        v = fminf(v, __shfl_xor(v, 1));
        v = fminf(v, __shfl_xor(v, 2));
        v = fminf(v, __shfl_xor(v, 4));
        v = fminf(v, __shfl_xor(v, 8));
        vmin[r] = v;   // all 16 lanes of quad q hold min over n for pixel p0+q*4+r
    }
    if (m < 4) {
        float v = (m==0) ? vmin[0] : (m==1) ? vmin[1] : (m==2) ? vmin[2] : vmin[3];
        if (!(v > 0.f)) v = 0.f;     // clamp negatives and -0.0
        uint32_t key = __float_as_uint(v);
        int pix = p0 + q*4 + m;
        keys[(size_t)b*NPIX + pix] = key;
        atomicAdd(&h16[b*65536 + (key >> 16)], 1u);
    }
}

// ---------------- K2: scan 65536-bin histogram for RANK -> bin16, r2 ----------------
__global__ void k_sel16(const uint32_t* __restrict__ h16, uint32_t* __restrict__ sm) {
    int b = blockIdx.x, t = threadIdx.x;
    const uint32_t* h = h16 + b*65536;
    __shared__ uint32_t seg[256];
    __shared__ uint32_t pre[256];
    const uint4* h4 = (const uint4*)(h + t*256);
    uint32_t s = 0;
    for (int i = 0; i < 64; i++) { uint4 v = h4[i]; s += v.x + v.y + v.z + v.w; }
    seg[t] = s;
    __syncthreads();
    if (t == 0) { uint32_t c = 0; for (int i = 0; i < 256; i++) { pre[i] = c; c += seg[i]; } }
    __syncthreads();
    uint32_t r = RANK;
    if (pre[t] <= r && r < pre[t] + seg[t]) {
        uint32_t c = pre[t];
        for (int i = 0; i < 256; i++) {
            uint32_t hc = h[t*256 + i];
            if (r < c + hc) { sm[4 + b] = (uint32_t)(t*256 + i); sm[8 + b] = r - c; break; }
            c += hc;
        }
    }
}

// ---------------- K3: histogram low 16 bits among top16==bin16 ----------------
__global__ __launch_bounds__(256) void k_hist3(const uint32_t* __restrict__ keys,
        const uint32_t* __restrict__ sm, uint32_t* __restrict__ h3) {
    int b = blockIdx.y;
    int p = blockIdx.x*256 + threadIdx.x;
    uint32_t bin16 = sm[4 + b];
    uint32_t k = keys[b*NPIX + p];
    if ((k >> 16) == bin16) atomicAdd(&h3[b*65536 + (k & 0xffffu)], 1u);
}

// ---------------- K4: scan low-16 histogram for r2 -> exact threshold key ----------------
__global__ void k_sel3(const uint32_t* __restrict__ h3, uint32_t* __restrict__ sm) {
    int b = blockIdx.x, t = threadIdx.x;
    const uint32_t* h = h3 + b*65536;
    __shared__ uint32_t seg[256];
    __shared__ uint32_t pre[256];
    const uint4* h4 = (const uint4*)(h + t*256);
    uint32_t s = 0;
    for (int i = 0; i < 64; i++) { uint4 v = h4[i]; s += v.x + v.y + v.z + v.w; }
    seg[t] = s;
    __syncthreads();
    if (t == 0) { uint32_t c = 0; for (int i = 0; i < 256; i++) { pre[i] = c; c += seg[i]; } }
    __syncthreads();
    uint32_t r = sm[8 + b];
    if (pre[t] <= r && r < pre[t] + seg[t]) {
        uint32_t c = pre[t];
        for (int i = 0; i < 256; i++) {
            uint32_t hc = h[t*256 + i];
            if (r < c + hc) { sm[12 + b] = (sm[4 + b] << 16) | (uint32_t)(t*256 + i); break; }
            c += hc;
        }
    }
}

// ---------------- K5: init union-find parents from mask ----------------
__global__ void k_initp(const uint32_t* __restrict__ keys, const uint32_t* __restrict__ sm,
                        int* __restrict__ P) {
    int b = blockIdx.y;
    int p = blockIdx.x*256 + threadIdx.x;
    uint32_t thr = sm[12 + b];
    P[b*NPIX + p] = (keys[b*NPIX + p] >= thr) ? p : -1;
}

// ---------------- K6: union-find CCL (8-connected) ----------------
__device__ __forceinline__ int uf_find(int* P, int x) {
    while (true) {
        int p = P[x];
        if (p == x) return x;
        int gp = P[p];
        if (gp != p) P[x] = gp;   // path halving (benign race)
        x = gp;
    }
}

__device__ __forceinline__ void uf_unite(int* P, int a, int b) {
    while (true) {
        a = uf_find(P, a);
        b = uf_find(P, b);
        if (a == b) return;
        if (a > b) { int t = a; a = b; b = t; }
        int old = atomicCAS(&P[b], b, a);   // device-scope
        if (old == b) return;
        b = old;
    }
}

__global__ void k_union(int* __restrict__ Pg) {
    int b = blockIdx.y;
    int p = blockIdx.x*256 + threadIdx.x;
    int* P = Pg + b*NPIX;
    if (P[p] == -1) return;
    int y = p >> 8, x = p & 255;
    if (x > 0      && P[p-1]      != -1) uf_unite(P, p, p-1);
    if (y > 0) {
        if (          P[p-WW]     != -1) uf_unite(P, p, p-WW);
        if (x > 0  && P[p-WW-1]   != -1) uf_unite(P, p, p-WW-1);
        if (x < WW-1 && P[p-WW+1] != -1) uf_unite(P, p, p-WW+1);
    }
}

// ---------------- K7: count merged pairs at centers + finish ----------------
__global__ void k_pairs_fin(const int* __restrict__ centers, int* __restrict__ Pg,
                            float* __restrict__ out) {
    __shared__ int ids[BB*NN];
    __shared__ int total;
    int t = threadIdx.x;
    if (t == 0) total = 0;
    __syncthreads();
    if (t < BB*NN) {
        int b = t >> 5;
        int cy = centers[t*2 + 0];
        int cx = centers[t*2 + 1];
        int p = cy*WW + cx;
        const int* P = Pg + b*NPIX;
        int id = P[p];
        if (id != -1) {
            int x = p;
            while (true) { int q = P[x]; if (q == x) break; x = q; }
            id = x;
        }
        ids[t] = id;
    }
    __syncthreads();
    int cnt = 0;
    if (t < BB*NN) {
        int b = t >> 5, n = t & 31;
        int id = ids[t];
        if (id != -1) for (int j = n+1; j < NN; j++) cnt += (ids[b*NN + j] == id);
    }
    atomicAdd(&total, cnt);
    __syncthreads();
    if (t == 0) out[0] = (float)total / TOTAL_PAIRS;
}

extern "C" void kernel_launch(void* const* d_in, const int* in_sizes, int n_in,
                              void* d_out, int out_size, void* d_ws, size_t ws_size,
                              hipStream_t stream) {
    const float* feat   = (const float*)d_in[0];
    const int* centers  = (const int*)d_in[1];
    float* out          = (float*)d_out;
    char* ws            = (char*)d_ws;

    uint32_t* sm     = (uint32_t*)(ws + OFF_SM);
    uint32_t* h16    = (uint32_t*)(ws + OFF_H16);
    uint32_t* h3     = (uint32_t*)(ws + OFF_H3);
    short*    gsplit = (short*)(ws + OFF_GSPLIT);
    float*    gnorm  = (float*)(ws + OFF_GN);
    uint32_t* keys   = (uint32_t*)(ws + OFF_KEYS);
    int*      P      = (int*)(ws + OFF_P);

    hipMemsetAsync(ws, 0, MEMSET_BYTES, stream);   // sm + h16 + h3

    dim3 gridPix(NPIX/256, BB);
    dim3 gridMM(NPIX/64, BB);

    k_gather    <<<BB*NN, CC, 0, stream>>>(feat, centers, gsplit, gnorm);
    k_d2mfma    <<<gridMM, 256, 0, stream>>>(feat, gsplit, gnorm, keys, h16);
    k_sel16     <<<BB, 256, 0, stream>>>(h16, sm);
    k_hist3     <<<gridPix, 256, 0, stream>>>(keys, sm, h3);
    k_sel3      <<<BB, 256, 0, stream>>>(h3, sm);
    k_initp     <<<gridPix, 256, 0, stream>>>(keys, sm, P);
    k_union     <<<gridPix, 256, 0, stream>>>(P);
    k_pairs_fin <<<1, 256, 0, stream>>>(centers, P, out);
}